// Round 18
// baseline (296.320 us; speedup 1.0000x reference)
//
#include <hip/hip_runtime.h>
#include <hip/hip_bf16.h>
#include <math.h>

#define NN 64
#define CC 96
#define HH 18
#define WW 32
#define HWP 576
#define SIN 320
#define NHEADS 4
#define HDIM 24
#define HIDC 96
#define ENCC 320

// ws layout (floats).
#define MOD_OFF   0
#define A_OFF     12288
#define Y_OFF     (A_OFF)
#define Z_OFF     (A_OFF + 3538944)
#define RH_OFF    (A_OFF + 7077888)
#define O_OFF     (A_OFF + 10616832)
#define HN_OFF    (O_OFF)
#define PART_OFF  (O_OFF + 3538944)
#define WTZR_OFF  (PART_OFF + 163840)
#define WTC_OFF   (WTZR_OFF + 165888)

typedef __attribute__((ext_vector_type(8))) short short8;
typedef __attribute__((ext_vector_type(4))) float f32x4;
typedef __attribute__((ext_vector_type(2))) unsigned int uint2v;
#define MFMA16(a, b, c) __builtin_amdgcn_mfma_f32_16x16x32_bf16(a, b, c, 0, 0, 0)

__device__ inline unsigned short f2bf(float f) {
  __hip_bfloat16 h = __float2bfloat16(f);
  return *reinterpret_cast<unsigned short*>(&h);
}
__device__ inline unsigned int cvtpk(float lo, float hi) {
  unsigned int r;
  asm volatile("v_cvt_pk_bf16_f32 %0, %1, %2" : "=v"(r) : "v"(lo), "v"(hi));
  return r;
}
union S8U { short8 s; unsigned int u[4]; };

// ---------------- fused prelude: modulation + weight transpose ----------------
__global__ __launch_bounds__(256) void k_modwt(const float* __restrict__ xs,
    const float* __restrict__ Wm, const float* __restrict__ bm,
    float* __restrict__ mod, const float* __restrict__ Kzr,
    const float* __restrict__ Kc, short* __restrict__ wz,
    short* __restrict__ wc) {
  __shared__ float s[SIN];
  int bid = blockIdx.x;
  if (bid < 64) {
    int n = bid;
    for (int i = threadIdx.x; i < SIN; i += 256) s[i] = xs[n * SIN + i];
    __syncthreads();
    int j = threadIdx.x;
    if (j < 192) {
      float acc = bm[j];
      #pragma unroll 4
      for (int k = 0; k < SIN; ++k) acc = fmaf(s[k], Wm[k * 192 + j], acc);
      mod[n * 192 + j] = acc;
    }
  } else {
    int idx = (bid - 64) * 256 + threadIdx.x;
    if (idx < 36864) {
      int oc = idx / 192, ic = idx % 192;
      const float* src = Kzr + (size_t)idx * 9;
      #pragma unroll
      for (int t = 0; t < 9; ++t)
        wz[(t * 192 + oc) * 192 + ic] = (short)f2bf(src[t]);
    } else {
      int j = idx - 36864;
      if (j < 18432) {
        int oc = j / 192, ic = j % 192;
        const float* src = Kc + (size_t)j * 9;
        #pragma unroll
        for (int t = 0; t < 9; ++t)
          wc[(t * 96 + oc) * 192 + ic] = (short)f2bf(src[t]);
      }
    }
  }
}

// ---------------- FiLM + qkv GEMM (MFMA), 128 thr, j-half per block --------
// grid 768: n = id&63, rem = id>>6 (0..11): pt = rem%6, jh = rem/6.
__global__ __launch_bounds__(128) void k_qkv(const float* __restrict__ x,
    const float* __restrict__ mod, const float* __restrict__ Wq,
    const float* __restrict__ bq, float* __restrict__ qkv) {
  int id = blockIdx.x;
  int n = id & 63, rem = id >> 6;
  int pt = rem % 6, jh = rem / 6;
  int p0 = pt * 96;
  __shared__ __align__(16) short XT[96 * 104];
  int tid = threadIdx.x, lane = tid & 63, wr = tid >> 6;
  int cl = lane & 15, kg = lane >> 4;
  #pragma unroll
  for (int w = 0; w < 18; ++w) {
    int lin = tid + 128 * w;
    int cp = lin / 48, pp = (lin % 48) * 2;
    float mA = mod[n * 192 + 2 * cp], bA = mod[n * 192 + 96 + 2 * cp];
    float mB = mod[n * 192 + 2 * cp + 1], bB = mod[n * 192 + 96 + 2 * cp + 1];
    float2 xa = *reinterpret_cast<const float2*>(
        &x[((size_t)n * CC + 2 * cp) * HWP + p0 + pp]);
    float2 xb = *reinterpret_cast<const float2*>(
        &x[((size_t)n * CC + 2 * cp + 1) * HWP + p0 + pp]);
    *reinterpret_cast<unsigned int*>(&XT[pp * 104 + 2 * cp]) =
        cvtpk(fmaf(xa.x, mA, bA), fmaf(xb.x, mB, bB));
    *reinterpret_cast<unsigned int*>(&XT[(pp + 1) * 104 + 2 * cp]) =
        cvtpk(fmaf(xa.y, mA, bA), fmaf(xb.y, mB, bB));
  }
  __syncthreads();

  f32x4 acc[3][9];
  #pragma unroll
  for (int mt = 0; mt < 3; ++mt)
    #pragma unroll
    for (int nt = 0; nt < 9; ++nt) acc[mt][nt] = (f32x4){0.f, 0.f, 0.f, 0.f};

  #pragma unroll
  for (int kc = 0; kc < 3; ++kc) {
    short8 af[3];
    #pragma unroll
    for (int mt = 0; mt < 3; ++mt) {
      int row = wr * 48 + mt * 16 + cl;
      af[mt] = *reinterpret_cast<const short8*>(
          &XT[row * 104 + kc * 32 + kg * 8]);
    }
    #pragma unroll
    for (int nt = 0; nt < 9; ++nt) {
      int j = jh * 144 + nt * 16 + cl;
      const float* wp = Wq + (size_t)(kc * 32 + kg * 8) * 288 + j;
      S8U b;
      b.u[0] = cvtpk(wp[0], wp[288]);
      b.u[1] = cvtpk(wp[576], wp[864]);
      b.u[2] = cvtpk(wp[1152], wp[1440]);
      b.u[3] = cvtpk(wp[1728], wp[2016]);
      #pragma unroll
      for (int mt = 0; mt < 3; ++mt)
        acc[mt][nt] = MFMA16(af[mt], b.s, acc[mt][nt]);
    }
  }

  #pragma unroll
  for (int nt = 0; nt < 9; ++nt) {
    int j = jh * 144 + nt * 16 + cl;
    float bias = bq[j];
    #pragma unroll
    for (int mt = 0; mt < 3; ++mt) {
      int pr = p0 + wr * 48 + mt * 16 + kg * 4;
      float* dst = qkv + ((size_t)n * HWP + pr) * 288 + j;
      dst[0] = acc[mt][nt][0] + bias;
      dst[288] = acc[mt][nt][1] + bias;
      dst[576] = acc[mt][nt][2] + bias;
      dst[864] = acc[mt][nt][3] + bias;
    }
  }
}

// ---------------- MFMA flash attention (unchanged) ----------------
__global__ __launch_bounds__(256) void k_attn(const float* __restrict__ qkv,
                                              float* __restrict__ o) {
  int id = blockIdx.x;
  int n = id & 63, head = id >> 6;
  __shared__ __align__(16) short K_lds[576 * 40];
  __shared__ __align__(16) short VT_lds[24 * 584];
  __shared__ __align__(16) short P_lds[4 * 144 * 40];
  int tid = threadIdx.x, lane = tid & 63, wid = tid >> 6;
  int cl = lane & 15, kg = lane >> 4;
  const float* base = qkv + (size_t)n * HWP * 288;
  int qoff = head * HDIM, koff = CC + head * HDIM, voff = 2 * CC + head * HDIM;
  const float scale = 0.2041241452319315f;

  for (int p = tid; p < HWP; p += 256) {
    const float* ksrc = base + (size_t)p * 288 + koff;
    #pragma unroll
    for (int g = 0; g < 3; ++g) {
      float4 a = *(const float4*)(ksrc + g * 8);
      float4 b = *(const float4*)(ksrc + g * 8 + 4);
      S8U t;
      t.u[0] = cvtpk(a.x, a.y); t.u[1] = cvtpk(a.z, a.w);
      t.u[2] = cvtpk(b.x, b.y); t.u[3] = cvtpk(b.z, b.w);
      *reinterpret_cast<short8*>(&K_lds[p * 40 + g * 8]) = t.s;
    }
    *reinterpret_cast<short8*>(&K_lds[p * 40 + 24]) =
        (short8){0, 0, 0, 0, 0, 0, 0, 0};
    const float* vsrc = base + (size_t)p * 288 + voff;
    #pragma unroll
    for (int d = 0; d < HDIM; ++d) VT_lds[d * 584 + p] = (short)f2bf(vsrc[d]);
  }

  int qbase = wid * 144;
  short8 qf[9];
  #pragma unroll
  for (int qt = 0; qt < 9; ++qt) {
    if (kg < 3) {
      const float* qs =
          base + (size_t)(qbase + qt * 16 + cl) * 288 + qoff + kg * 8;
      float4 a = *(const float4*)qs;
      float4 b = *(const float4*)(qs + 4);
      S8U t;
      t.u[0] = cvtpk(a.x * scale, a.y * scale);
      t.u[1] = cvtpk(a.z * scale, a.w * scale);
      t.u[2] = cvtpk(b.x * scale, b.y * scale);
      t.u[3] = cvtpk(b.z * scale, b.w * scale);
      qf[qt] = t.s;
    } else {
      qf[qt] = (short8){0, 0, 0, 0, 0, 0, 0, 0};
    }
  }
  __syncthreads();

  f32x4 acc[9][2];
  float m[9], l[9];
  #pragma unroll
  for (int qt = 0; qt < 9; ++qt) {
    acc[qt][0] = (f32x4){0.f, 0.f, 0.f, 0.f};
    acc[qt][1] = (f32x4){0.f, 0.f, 0.f, 0.f};
    m[qt] = -1e30f; l[qt] = 0.f;
  }
  short* pw = P_lds + wid * 5760;
  const f32x4 z4 = (f32x4){0.f, 0.f, 0.f, 0.f};

  for (int ch = 0; ch < 18; ++ch) {
    int key0 = ch * 32;
    short8 ka0 = *reinterpret_cast<const short8*>(
        &K_lds[(key0 + cl) * 40 + kg * 8]);
    short8 ka1 = *reinterpret_cast<const short8*>(
        &K_lds[(key0 + 16 + cl) * 40 + kg * 8]);
    #pragma unroll
    for (int qt = 0; qt < 9; ++qt) {
      f32x4 s0 = MFMA16(ka0, qf[qt], z4);
      f32x4 s1 = MFMA16(ka1, qf[qt], z4);
      float mx = fmaxf(fmaxf(fmaxf(s0[0], s0[1]), fmaxf(s0[2], s0[3])),
                       fmaxf(fmaxf(s1[0], s1[1]), fmaxf(s1[2], s1[3])));
      mx = fmaxf(mx, __shfl_xor(mx, 16));
      mx = fmaxf(mx, __shfl_xor(mx, 32));
      float mn = fmaxf(m[qt], mx);
      float corr = __expf(m[qt] - mn);
      float p0 = __expf(s0[0] - mn), p1 = __expf(s0[1] - mn);
      float p2 = __expf(s0[2] - mn), p3 = __expf(s0[3] - mn);
      float p4 = __expf(s1[0] - mn), p5 = __expf(s1[1] - mn);
      float p6 = __expf(s1[2] - mn), p7 = __expf(s1[3] - mn);
      float sum = ((p0 + p1) + (p2 + p3)) + ((p4 + p5) + (p6 + p7));
      sum += __shfl_xor(sum, 16);
      sum += __shfl_xor(sum, 32);
      l[qt] = l[qt] * corr + sum;
      m[qt] = mn;
      float c0 = __shfl(corr, kg * 4 + 0);
      float c1 = __shfl(corr, kg * 4 + 1);
      float c2 = __shfl(corr, kg * 4 + 2);
      float c3 = __shfl(corr, kg * 4 + 3);
      acc[qt][0][0] *= c0; acc[qt][0][1] *= c1;
      acc[qt][0][2] *= c2; acc[qt][0][3] *= c3;
      acc[qt][1][0] *= c0; acc[qt][1][1] *= c1;
      acc[qt][1][2] *= c2; acc[qt][1][3] *= c3;
      uint2v w0 = {cvtpk(p0, p1), cvtpk(p2, p3)};
      uint2v w1 = {cvtpk(p4, p5), cvtpk(p6, p7)};
      short* prow = pw + (qt * 16 + cl) * 40;
      *reinterpret_cast<uint2v*>(&prow[4 * kg]) = w0;
      *reinterpret_cast<uint2v*>(&prow[16 + 4 * kg]) = w1;
    }
    short8 vb0 = *reinterpret_cast<const short8*>(
        &VT_lds[cl * 584 + key0 + kg * 8]);
    short8 vb1 = (cl < 8) ? *reinterpret_cast<const short8*>(
                                &VT_lds[(16 + cl) * 584 + key0 + kg * 8])
                          : (short8){0, 0, 0, 0, 0, 0, 0, 0};
    #pragma unroll
    for (int qt = 0; qt < 9; ++qt) {
      short8 pa = *reinterpret_cast<const short8*>(
          &pw[(qt * 16 + cl) * 40 + kg * 8]);
      acc[qt][0] = MFMA16(pa, vb0, acc[qt][0]);
      acc[qt][1] = MFMA16(pa, vb1, acc[qt][1]);
    }
  }

  #pragma unroll
  for (int qt = 0; qt < 9; ++qt) {
    float li0 = 1.f / __shfl(l[qt], kg * 4 + 0);
    float li1 = 1.f / __shfl(l[qt], kg * 4 + 1);
    float li2 = 1.f / __shfl(l[qt], kg * 4 + 2);
    float li3 = 1.f / __shfl(l[qt], kg * 4 + 3);
    #pragma unroll
    for (int dt = 0; dt < 2; ++dt) {
      int d = dt * 16 + cl;
      if (dt == 1 && cl >= 8) continue;
      size_t ob = ((size_t)n * HWP + qbase + qt * 16 + kg * 4) * CC
                  + head * HDIM + d;
      o[ob] = acc[qt][dt][0] * li0;
      o[ob + CC] = acc[qt][dt][1] * li1;
      o[ob + 2 * CC] = acc[qt][dt][2] * li2;
      o[ob + 3 * CC] = acc[qt][dt][3] * li3;
    }
  }
}

// ---------------- proj + residual (MFMA), 128 thr, j-half per block --------
__global__ __launch_bounds__(128) void k_proj(const float* __restrict__ o,
    const float* __restrict__ Wp, const float* __restrict__ bp,
    const float* __restrict__ x, float* __restrict__ y) {
  int id = blockIdx.x;
  int n = id & 63, rem = id >> 6;
  int pt = rem % 6, jh = rem / 6;
  int p0 = pt * 96;
  __shared__ __align__(16) short XT[96 * 104];
  int tid = threadIdx.x, lane = tid & 63, wr = tid >> 6;
  int cl = lane & 15, kg = lane >> 4;
  #pragma unroll
  for (int w = 0; w < 18; ++w) {
    int lin = tid + 128 * w;
    int p = lin / 24, cg = lin % 24;
    float4 v = *reinterpret_cast<const float4*>(
        &o[((size_t)n * HWP + p0 + p) * CC + cg * 4]);
    uint2v u = {cvtpk(v.x, v.y), cvtpk(v.z, v.w)};
    *reinterpret_cast<uint2v*>(&XT[p * 104 + cg * 4]) = u;
  }
  __syncthreads();

  f32x4 acc[3][3];
  #pragma unroll
  for (int mt = 0; mt < 3; ++mt)
    #pragma unroll
    for (int nt = 0; nt < 3; ++nt) acc[mt][nt] = (f32x4){0.f, 0.f, 0.f, 0.f};

  #pragma unroll
  for (int kc = 0; kc < 3; ++kc) {
    short8 af[3];
    #pragma unroll
    for (int mt = 0; mt < 3; ++mt) {
      int row = wr * 48 + mt * 16 + cl;
      af[mt] = *reinterpret_cast<const short8*>(
          &XT[row * 104 + kc * 32 + kg * 8]);
    }
    #pragma unroll
    for (int nt = 0; nt < 3; ++nt) {
      int j = jh * 48 + nt * 16 + cl;
      const float* wp = Wp + (size_t)(kc * 32 + kg * 8) * 96 + j;
      S8U b;
      b.u[0] = cvtpk(wp[0], wp[96]);
      b.u[1] = cvtpk(wp[192], wp[288]);
      b.u[2] = cvtpk(wp[384], wp[480]);
      b.u[3] = cvtpk(wp[576], wp[672]);
      #pragma unroll
      for (int mt = 0; mt < 3; ++mt)
        acc[mt][nt] = MFMA16(af[mt], b.s, acc[mt][nt]);
    }
  }

  #pragma unroll
  for (int nt = 0; nt < 3; ++nt) {
    int j = jh * 48 + nt * 16 + cl;
    float bias = bp[j];
    #pragma unroll
    for (int mt = 0; mt < 3; ++mt) {
      int pr = p0 + wr * 48 + mt * 16 + kg * 4;
      size_t yi = ((size_t)n * CC + j) * HWP + pr;
      float4 xv = *reinterpret_cast<const float4*>(&x[yi]);
      float4 o4 = {xv.x + acc[mt][nt][0] + bias, xv.y + acc[mt][nt][1] + bias,
                   xv.z + acc[mt][nt][2] + bias, xv.w + acc[mt][nt][3] + bias};
      *reinterpret_cast<float4*>(&y[yi]) = o4;
    }
  }
}

// ======================= MFMA convs =======================
// conv_zr unchanged (round-17, balanced at 3 blocks/CU).

__global__ __launch_bounds__(256) void k_conv_zr(const float* __restrict__ y,
    const float* __restrict__ hidden, const int* __restrict__ keys,
    const short* __restrict__ wt, const float* __restrict__ bb,
    float* __restrict__ z, float* __restrict__ rh) {
  int id = blockIdx.x;
  int n = id & 63, b = id >> 6;
  int bp = b % 6, bo = b / 6;
  int key = keys[n];
  int ocb = bo * 96;
  __shared__ __align__(16) short XT[170 * 68];
  int tid = threadIdx.x;
  int lane = tid & 63, wid = tid >> 6;
  int wr = wid >> 1, wc = wid & 1;
  int col = lane & 15, kg = lane >> 4;
  int icp = tid >> 4, psub = tid & 15;
  int pg0 = (3 * bp - 1) * 32;
  unsigned int* XTu = reinterpret_cast<unsigned int*>(XT);

  for (int i = tid; i < 5780; i += 256) XTu[i] = 0;

  f32x4 acc[3][3];
  #pragma unroll
  for (int m = 0; m < 3; ++m)
    #pragma unroll
    for (int nt = 0; nt < 3; ++nt) acc[m][nt] = (f32x4){0.f, 0.f, 0.f, 0.f};
  int rowm[3], pxm[3];
  #pragma unroll
  for (int m = 0; m < 3; ++m) {
    int pl = wr * 48 + m * 16 + col;
    rowm[m] = pl >> 5;
    pxm[m] = pl & 31;
  }
  int wl = (ocb + wc * 48 + col) * 192 + kg * 8;
  const float* hsrc = hidden + (size_t)key * HIDC * HWP;
  __syncthreads();

  #pragma unroll
  for (int ph = 0; ph < 3; ++ph) {
    #pragma unroll
    for (int c = 0; c < 2; ++c) {
      int gc = ph * 64 + c * 32;
      const float* s0 = (gc < 96)
          ? y + ((size_t)n * CC + gc + 2 * icp) * HWP
          : hsrc + (size_t)(gc - 96 + 2 * icp) * HWP;
      const float* s1 = s0 + HWP;
      #pragma unroll
      for (int j = 0; j < 5; ++j) {
        int pos = 32 * j + 2 * psub;
        int pg = pg0 + pos;
        bool ok = (pg >= 0 && pg < HWP);
        float2 a = ok ? *reinterpret_cast<const float2*>(s0 + pg)
                      : float2{0.f, 0.f};
        float2 bv = ok ? *reinterpret_cast<const float2*>(s1 + pg)
                       : float2{0.f, 0.f};
        int pidx0 = j * 34 + 1 + 2 * psub;
        XTu[pidx0 * 34 + c * 16 + icp] = cvtpk(a.x, bv.x);
        XTu[(pidx0 + 1) * 34 + c * 16 + icp] = cvtpk(a.y, bv.y);
      }
    }
    __syncthreads();
    #pragma unroll 3
    for (int t = 0; t < 9; ++t) {
      int dyp = t / 3, dxp = t % 3;
      const short* wci = wt + wl + t * 36864 + ph * 64;
      #pragma unroll
      for (int qc = 0; qc < 2; ++qc) {
        short8 b0 = *reinterpret_cast<const short8*>(wci + qc * 32);
        short8 b1 = *reinterpret_cast<const short8*>(wci + qc * 32 + 3072);
        short8 b2 = *reinterpret_cast<const short8*>(wci + qc * 32 + 6144);
        #pragma unroll
        for (int m = 0; m < 3; ++m) {
          int pidx = (rowm[m] + dyp) * 34 + pxm[m] + dxp;
          short8 a = *reinterpret_cast<const short8*>(
              XT + pidx * 68 + qc * 32 + kg * 8);
          acc[m][0] = MFMA16(a, b0, acc[m][0]);
          acc[m][1] = MFMA16(a, b1, acc[m][1]);
          acc[m][2] = MFMA16(a, b2, acc[m][2]);
        }
      }
    }
    __syncthreads();
  }

  #pragma unroll
  for (int nt = 0; nt < 3; ++nt) {
    int oc = ocb + wc * 48 + nt * 16 + col;
    float bias = bb[oc];
    #pragma unroll
    for (int m = 0; m < 3; ++m) {
      int p0 = bp * 96 + wr * 48 + m * 16 + kg * 4;
      f32x4 v = acc[m][nt];
      float e0 = 1.f / (1.f + __expf(-(v[0] + bias)));
      float e1 = 1.f / (1.f + __expf(-(v[1] + bias)));
      float e2 = 1.f / (1.f + __expf(-(v[2] + bias)));
      float e3 = 1.f / (1.f + __expf(-(v[3] + bias)));
      if (oc < CC) {
        float4 o4 = {e0, e1, e2, e3};
        *reinterpret_cast<float4*>(&z[((size_t)n * CC + oc) * HWP + p0]) = o4;
      } else {
        int c2 = oc - CC;
        float4 h4 = *reinterpret_cast<const float4*>(
            &hidden[((size_t)key * HIDC + c2) * HWP + p0]);
        float4 o4 = {e0 * h4.x, e1 * h4.y, e2 * h4.z, e3 * h4.w};
        *reinterpret_cast<float4*>(&rh[((size_t)n * CC + c2) * HWP + p0]) = o4;
      }
    }
  }
}

// conv c: 128 thr, oc-half per block. grid 768: n=id&63, rem=id>>6:
// bp = rem%6, och = rem/6.
__global__ __launch_bounds__(128) void k_conv_c(const float* __restrict__ y,
    const float* __restrict__ rh, const int* __restrict__ keys,
    const float* __restrict__ z, const float* __restrict__ hidden,
    const short* __restrict__ wt, const float* __restrict__ bb,
    float* __restrict__ hn) {
  int id = blockIdx.x;
  int n = id & 63, rem = id >> 6;
  int bp = rem % 6, och = rem / 6;
  int key = keys[n];
  __shared__ __align__(16) short XT[170 * 68];
  int tid = threadIdx.x;
  int lane = tid & 63, wr = tid >> 6;
  int col = lane & 15, kg = lane >> 4;
  int icp = tid >> 4, psub = tid & 15;  // icp in 0..7
  int pg0 = (3 * bp - 1) * 32;
  unsigned int* XTu = reinterpret_cast<unsigned int*>(XT);

  for (int i = tid; i < 5780; i += 128) XTu[i] = 0;

  f32x4 acc[3][3];
  #pragma unroll
  for (int m = 0; m < 3; ++m)
    #pragma unroll
    for (int nt = 0; nt < 3; ++nt) acc[m][nt] = (f32x4){0.f, 0.f, 0.f, 0.f};
  int rowm[3], pxm[3];
  #pragma unroll
  for (int m = 0; m < 3; ++m) {
    int pl = wr * 48 + m * 16 + col;
    rowm[m] = pl >> 5;
    pxm[m] = pl & 31;
  }
  int wl = (och * 48 + col) * 192 + kg * 8;
  const float* rsrc = rh + (size_t)n * CC * HWP;
  __syncthreads();

  #pragma unroll
  for (int ph = 0; ph < 3; ++ph) {
    // stage 64 channels: 4 passes of 16 ch (icp covers 8 ch-pairs)
    #pragma unroll
    for (int c = 0; c < 4; ++c) {
      int gc = ph * 64 + c * 16;
      const float* s0 = (gc < 96)
          ? y + ((size_t)n * CC + gc + 2 * icp) * HWP
          : rsrc + (size_t)(gc - 96 + 2 * icp) * HWP;
      const float* s1 = s0 + HWP;
      #pragma unroll
      for (int j = 0; j < 5; ++j) {
        int pos = 32 * j + 2 * psub;
        int pg = pg0 + pos;
        bool ok = (pg >= 0 && pg < HWP);
        float2 a = ok ? *reinterpret_cast<const float2*>(s0 + pg)
                      : float2{0.f, 0.f};
        float2 bv = ok ? *reinterpret_cast<const float2*>(s1 + pg)
                       : float2{0.f, 0.f};
        int pidx0 = j * 34 + 1 + 2 * psub;
        XTu[pidx0 * 34 + c * 8 + icp] = cvtpk(a.x, bv.x);
        XTu[(pidx0 + 1) * 34 + c * 8 + icp] = cvtpk(a.y, bv.y);
      }
    }
    __syncthreads();
    #pragma unroll 3
    for (int t = 0; t < 9; ++t) {
      int dyp = t / 3, dxp = t % 3;
      const short* wci = wt + wl + t * 18432 + ph * 64;
      #pragma unroll
      for (int qc = 0; qc < 2; ++qc) {
        short8 b0 = *reinterpret_cast<const short8*>(wci + qc * 32);
        short8 b1 = *reinterpret_cast<const short8*>(wci + qc * 32 + 3072);
        short8 b2 = *reinterpret_cast<const short8*>(wci + qc * 32 + 6144);
        #pragma unroll
        for (int m = 0; m < 3; ++m) {
          int pidx = (rowm[m] + dyp) * 34 + pxm[m] + dxp;
          short8 a = *reinterpret_cast<const short8*>(
              XT + pidx * 68 + qc * 32 + kg * 8);
          acc[m][0] = MFMA16(a, b0, acc[m][0]);
          acc[m][1] = MFMA16(a, b1, acc[m][1]);
          acc[m][2] = MFMA16(a, b2, acc[m][2]);
        }
      }
    }
    __syncthreads();
  }

  #pragma unroll
  for (int nt = 0; nt < 3; ++nt) {
    int oc = och * 48 + nt * 16 + col;
    float bias = bb[oc];
    #pragma unroll
    for (int m = 0; m < 3; ++m) {
      int p0 = bp * 96 + wr * 48 + m * 16 + kg * 4;
      f32x4 v = acc[m][nt];
      float c0 = tanhf(v[0] + bias);
      float c1 = tanhf(v[1] + bias);
      float c2v = tanhf(v[2] + bias);
      float c3 = tanhf(v[3] + bias);
      float4 z4 = *reinterpret_cast<const float4*>(
          &z[((size_t)n * CC + oc) * HWP + p0]);
      float4 h4 = *reinterpret_cast<const float4*>(
          &hidden[((size_t)key * HIDC + oc) * HWP + p0]);
      float4 o4 = {(1.f - z4.x) * h4.x + z4.x * c0,
                   (1.f - z4.y) * h4.y + z4.y * c1,
                   (1.f - z4.z) * h4.z + z4.z * c2v,
                   (1.f - z4.w) * h4.w + z4.w * c3};
      *reinterpret_cast<float4*>(&hn[((size_t)n * CC + oc) * HWP + p0]) = o4;
    }
  }
}

// ---------------- PosConv (MFMA) + fused pool, 128 thr, oc-half/block ------
__global__ __launch_bounds__(128) void k_enc(const float* __restrict__ hn,
    const float* __restrict__ pos, const float* __restrict__ Wp,
    float* __restrict__ part, float* __restrict__ out) {
  int id = blockIdx.x;
  int n = id & 63, rem = id >> 6;
  int pt = rem % 6, wcn = rem / 6;
  int p0 = pt * 96;
  __shared__ __align__(16) short XT[96 * 104];
  int tid = threadIdx.x, lane = tid & 63, wr = tid >> 6;
  int cl = lane & 15, kg = lane >> 4;

  // fused pool: 9 x 128 = 1152 outputs per block (768 * 1152 = 884736)
  #pragma unroll
  for (int r = 0; r < 9; ++r) {
    int idx = id * 1152 + r * 128 + tid;
    int jj = idx & 15, ii = (idx >> 4) % 9, nc = idx / 144;
    const float* bsrc = hn + (size_t)nc * HWP + (2 * ii) * WW + 2 * jj;
    out[idx] = 0.25f * (bsrc[0] + bsrc[1] + bsrc[WW] + bsrc[WW + 1]);
  }

  #pragma unroll
  for (int w = 0; w < 18; ++w) {
    int lin = tid + 128 * w;
    int cp = lin / 48, pp = (lin % 48) * 2;
    float2 ha = *reinterpret_cast<const float2*>(
        &hn[((size_t)n * CC + 2 * cp) * HWP + p0 + pp]);
    float2 hb = *reinterpret_cast<const float2*>(
        &hn[((size_t)n * CC + 2 * cp + 1) * HWP + p0 + pp]);
    float2 pa = *reinterpret_cast<const float2*>(&pos[(2 * cp) * HWP + p0 + pp]);
    float2 pc = *reinterpret_cast<const float2*>(
        &pos[(2 * cp + 1) * HWP + p0 + pp]);
    *reinterpret_cast<unsigned int*>(&XT[pp * 104 + 2 * cp]) =
        cvtpk(ha.x + pa.x, hb.x + pc.x);
    *reinterpret_cast<unsigned int*>(&XT[(pp + 1) * 104 + 2 * cp]) =
        cvtpk(ha.y + pa.y, hb.y + pc.y);
  }
  __syncthreads();

  f32x4 acc[3][10];
  #pragma unroll
  for (int mt = 0; mt < 3; ++mt)
    #pragma unroll
    for (int nt = 0; nt < 10; ++nt) acc[mt][nt] = (f32x4){0.f, 0.f, 0.f, 0.f};

  #pragma unroll
  for (int kc = 0; kc < 3; ++kc) {
    short8 af[3];
    #pragma unroll
    for (int mt = 0; mt < 3; ++mt) {
      int row = wr * 48 + mt * 16 + cl;
      af[mt] = *reinterpret_cast<const short8*>(
          &XT[row * 104 + kc * 32 + kg * 8]);
    }
    #pragma unroll
    for (int nt = 0; nt < 10; ++nt) {
      int oc = wcn * 160 + nt * 16 + cl;
      const float* wp = Wp + (size_t)oc * CC + kc * 32 + kg * 8;
      float4 w0 = *reinterpret_cast<const float4*>(wp);
      float4 w1 = *reinterpret_cast<const float4*>(wp + 4);
      S8U b;
      b.u[0] = cvtpk(w0.x, w0.y); b.u[1] = cvtpk(w0.z, w0.w);
      b.u[2] = cvtpk(w1.x, w1.y); b.u[3] = cvtpk(w1.z, w1.w);
      #pragma unroll
      for (int mt = 0; mt < 3; ++mt)
        acc[mt][nt] = MFMA16(af[mt], b.s, acc[mt][nt]);
    }
  }

  #pragma unroll
  for (int nt = 0; nt < 10; ++nt) {
    float mx = -1e30f;
    #pragma unroll
    for (int mt = 0; mt < 3; ++mt) {
      mx = fmaxf(mx, fmaxf(fmaxf(acc[mt][nt][0], acc[mt][nt][1]),
                           fmaxf(acc[mt][nt][2], acc[mt][nt][3])));
    }
    mx = fmaxf(mx, __shfl_xor(mx, 16));
    mx = fmaxf(mx, __shfl_xor(mx, 32));
    if (kg == 0) {
      int oc = wcn * 160 + nt * 16 + cl;
      part[(((size_t)n * 6 + pt) * 2 + wr) * ENCC + oc] = mx;
    }
  }
}

__global__ __launch_bounds__(320) void k_reduce(const float* __restrict__ part,
    const float* __restrict__ bpos, float* __restrict__ out) {
  int n = blockIdx.x, o = threadIdx.x;
  float mx = -1e30f;
  #pragma unroll
  for (int t = 0; t < 12; ++t)
    mx = fmaxf(mx, part[((size_t)n * 12 + t) * ENCC + o]);
  out[NN * CC * 144 + n * ENCC + o] = mx + bpos[o];
}

extern "C" void kernel_launch(void* const* d_in, const int* in_sizes, int n_in,
                              void* d_out, int out_size, void* d_ws, size_t ws_size,
                              hipStream_t stream) {
  const float* x       = (const float*)d_in[0];
  const float* x_state = (const float*)d_in[1];
  const int*   keys    = (const int*)d_in[2];
  const float* hidden  = (const float*)d_in[3];
  const float* W_mod   = (const float*)d_in[4];
  const float* b_mod   = (const float*)d_in[5];
  const float* W_qkv   = (const float*)d_in[6];
  const float* b_qkv   = (const float*)d_in[7];
  const float* W_proj  = (const float*)d_in[8];
  const float* b_proj  = (const float*)d_in[9];
  const float* K_zr    = (const float*)d_in[10];
  const float* b_zr    = (const float*)d_in[11];
  const float* K_c     = (const float*)d_in[12];
  const float* b_c     = (const float*)d_in[13];
  const float* pos_emb = (const float*)d_in[14];
  const float* W_pos   = (const float*)d_in[15];
  const float* b_pos   = (const float*)d_in[16];
  float* out = (float*)d_out;
  float* ws  = (float*)d_ws;
  short* wtzr = (short*)(ws + WTZR_OFF);
  short* wtc  = (short*)(ws + WTC_OFF);

  k_modwt<<<280, 256, 0, stream>>>(x_state, W_mod, b_mod, ws + MOD_OFF,
                                   K_zr, K_c, wtzr, wtc);
  k_qkv<<<768, 128, 0, stream>>>(x, ws + MOD_OFF, W_qkv, b_qkv, ws + A_OFF);
  k_attn<<<256, 256, 0, stream>>>(ws + A_OFF, ws + O_OFF);
  k_proj<<<768, 128, 0, stream>>>(ws + O_OFF, W_proj, b_proj, x, ws + Y_OFF);
  k_conv_zr<<<768, 256, 0, stream>>>(ws + Y_OFF, hidden, keys, wtzr, b_zr,
                                     ws + Z_OFF, ws + RH_OFF);
  k_conv_c<<<768, 128, 0, stream>>>(ws + Y_OFF, ws + RH_OFF, keys, ws + Z_OFF,
                                    hidden, wtc, b_c, ws + HN_OFF);
  k_enc<<<768, 128, 0, stream>>>(ws + HN_OFF, pos_emb, W_pos, ws + PART_OFF,
                                 out);
  k_reduce<<<NN, 320, 0, stream>>>(ws + PART_OFF, b_pos, out);
}

// Round 19
// 292.063 us; speedup vs baseline: 1.0146x; 1.0146x over previous
//
#include <hip/hip_runtime.h>
#include <hip/hip_bf16.h>
#include <math.h>

#define NN 64
#define CC 96
#define HH 18
#define WW 32
#define HWP 576
#define SIN 320
#define NHEADS 4
#define HDIM 24
#define HIDC 96
#define ENCC 320

// ws layout (floats).
#define MOD_OFF   0
#define A_OFF     12288
#define Y_OFF     (A_OFF)
#define Z_OFF     (A_OFF + 3538944)
#define RH_OFF    (A_OFF + 7077888)
#define O_OFF     (A_OFF + 10616832)
#define HN_OFF    (O_OFF)
#define PART_OFF  (O_OFF + 3538944)
#define WTZR_OFF  (PART_OFF + 163840)
#define WTC_OFF   (WTZR_OFF + 165888)

typedef __attribute__((ext_vector_type(8))) short short8;
typedef __attribute__((ext_vector_type(4))) float f32x4;
typedef __attribute__((ext_vector_type(2))) unsigned int uint2v;
#define MFMA16(a, b, c) __builtin_amdgcn_mfma_f32_16x16x32_bf16(a, b, c, 0, 0, 0)

__device__ inline unsigned short f2bf(float f) {
  __hip_bfloat16 h = __float2bfloat16(f);
  return *reinterpret_cast<unsigned short*>(&h);
}
__device__ inline unsigned int cvtpk(float lo, float hi) {
  unsigned int r;
  asm volatile("v_cvt_pk_bf16_f32 %0, %1, %2" : "=v"(r) : "v"(lo), "v"(hi));
  return r;
}
union S8U { short8 s; unsigned int u[4]; };

// ---------------- fused prelude: modulation + weight transpose ----------------
__global__ __launch_bounds__(256) void k_modwt(const float* __restrict__ xs,
    const float* __restrict__ Wm, const float* __restrict__ bm,
    float* __restrict__ mod, const float* __restrict__ Kzr,
    const float* __restrict__ Kc, short* __restrict__ wz,
    short* __restrict__ wc) {
  __shared__ float s[SIN];
  int bid = blockIdx.x;
  if (bid < 64) {
    int n = bid;
    for (int i = threadIdx.x; i < SIN; i += 256) s[i] = xs[n * SIN + i];
    __syncthreads();
    int j = threadIdx.x;
    if (j < 192) {
      float acc = bm[j];
      #pragma unroll 4
      for (int k = 0; k < SIN; ++k) acc = fmaf(s[k], Wm[k * 192 + j], acc);
      mod[n * 192 + j] = acc;
    }
  } else {
    int idx = (bid - 64) * 256 + threadIdx.x;
    if (idx < 36864) {
      int oc = idx / 192, ic = idx % 192;
      const float* src = Kzr + (size_t)idx * 9;
      #pragma unroll
      for (int t = 0; t < 9; ++t)
        wz[(t * 192 + oc) * 192 + ic] = (short)f2bf(src[t]);
    } else {
      int j = idx - 36864;
      if (j < 18432) {
        int oc = j / 192, ic = j % 192;
        const float* src = Kc + (size_t)j * 9;
        #pragma unroll
        for (int t = 0; t < 9; ++t)
          wc[(t * 96 + oc) * 192 + ic] = (short)f2bf(src[t]);
      }
    }
  }
}

// ---------------- FiLM + qkv GEMM (MFMA) ----------------
__global__ __launch_bounds__(256) void k_qkv(const float* __restrict__ x,
    const float* __restrict__ mod, const float* __restrict__ Wq,
    const float* __restrict__ bq, float* __restrict__ qkv) {
  int id = blockIdx.x;
  int n = id & 63, pt = id >> 6;
  int p0 = pt * 96;
  __shared__ __align__(16) short XT[96 * 104];
  int tid = threadIdx.x, lane = tid & 63, wid = tid >> 6;
  int wr = wid >> 1, wcn = wid & 1;
  int cl = lane & 15, kg = lane >> 4;
  #pragma unroll
  for (int w = 0; w < 9; ++w) {
    int lin = tid + 256 * w;
    int cp = lin / 48, pp = (lin % 48) * 2;
    float mA = mod[n * 192 + 2 * cp], bA = mod[n * 192 + 96 + 2 * cp];
    float mB = mod[n * 192 + 2 * cp + 1], bB = mod[n * 192 + 96 + 2 * cp + 1];
    float2 xa = *reinterpret_cast<const float2*>(
        &x[((size_t)n * CC + 2 * cp) * HWP + p0 + pp]);
    float2 xb = *reinterpret_cast<const float2*>(
        &x[((size_t)n * CC + 2 * cp + 1) * HWP + p0 + pp]);
    *reinterpret_cast<unsigned int*>(&XT[pp * 104 + 2 * cp]) =
        cvtpk(fmaf(xa.x, mA, bA), fmaf(xb.x, mB, bB));
    *reinterpret_cast<unsigned int*>(&XT[(pp + 1) * 104 + 2 * cp]) =
        cvtpk(fmaf(xa.y, mA, bA), fmaf(xb.y, mB, bB));
  }
  __syncthreads();

  f32x4 acc[3][9];
  #pragma unroll
  for (int mt = 0; mt < 3; ++mt)
    #pragma unroll
    for (int nt = 0; nt < 9; ++nt) acc[mt][nt] = (f32x4){0.f, 0.f, 0.f, 0.f};

  #pragma unroll
  for (int kc = 0; kc < 3; ++kc) {
    short8 af[3];
    #pragma unroll
    for (int mt = 0; mt < 3; ++mt) {
      int row = wr * 48 + mt * 16 + cl;
      af[mt] = *reinterpret_cast<const short8*>(
          &XT[row * 104 + kc * 32 + kg * 8]);
    }
    #pragma unroll
    for (int nt = 0; nt < 9; ++nt) {
      int j = wcn * 144 + nt * 16 + cl;
      const float* wp = Wq + (size_t)(kc * 32 + kg * 8) * 288 + j;
      S8U b;
      b.u[0] = cvtpk(wp[0], wp[288]);
      b.u[1] = cvtpk(wp[576], wp[864]);
      b.u[2] = cvtpk(wp[1152], wp[1440]);
      b.u[3] = cvtpk(wp[1728], wp[2016]);
      #pragma unroll
      for (int mt = 0; mt < 3; ++mt)
        acc[mt][nt] = MFMA16(af[mt], b.s, acc[mt][nt]);
    }
  }

  #pragma unroll
  for (int nt = 0; nt < 9; ++nt) {
    int j = wcn * 144 + nt * 16 + cl;
    float bias = bq[j];
    #pragma unroll
    for (int mt = 0; mt < 3; ++mt) {
      int pr = p0 + wr * 48 + mt * 16 + kg * 4;
      float* dst = qkv + ((size_t)n * HWP + pr) * 288 + j;
      dst[0] = acc[mt][nt][0] + bias;
      dst[288] = acc[mt][nt][1] + bias;
      dst[576] = acc[mt][nt][2] + bias;
      dst[864] = acc[mt][nt][3] + bias;
    }
  }
}

// ---------------- MFMA flash attention ----------------
__global__ __launch_bounds__(256) void k_attn(const float* __restrict__ qkv,
                                              float* __restrict__ o) {
  int id = blockIdx.x;
  int n = id & 63, head = id >> 6;
  __shared__ __align__(16) short K_lds[576 * 40];
  __shared__ __align__(16) short VT_lds[24 * 584];
  __shared__ __align__(16) short P_lds[4 * 144 * 40];
  int tid = threadIdx.x, lane = tid & 63, wid = tid >> 6;
  int cl = lane & 15, kg = lane >> 4;
  const float* base = qkv + (size_t)n * HWP * 288;
  int qoff = head * HDIM, koff = CC + head * HDIM, voff = 2 * CC + head * HDIM;
  const float scale = 0.2041241452319315f;

  for (int p = tid; p < HWP; p += 256) {
    const float* ksrc = base + (size_t)p * 288 + koff;
    #pragma unroll
    for (int g = 0; g < 3; ++g) {
      float4 a = *(const float4*)(ksrc + g * 8);
      float4 b = *(const float4*)(ksrc + g * 8 + 4);
      S8U t;
      t.u[0] = cvtpk(a.x, a.y); t.u[1] = cvtpk(a.z, a.w);
      t.u[2] = cvtpk(b.x, b.y); t.u[3] = cvtpk(b.z, b.w);
      *reinterpret_cast<short8*>(&K_lds[p * 40 + g * 8]) = t.s;
    }
    *reinterpret_cast<short8*>(&K_lds[p * 40 + 24]) =
        (short8){0, 0, 0, 0, 0, 0, 0, 0};
    const float* vsrc = base + (size_t)p * 288 + voff;
    #pragma unroll
    for (int d = 0; d < HDIM; ++d) VT_lds[d * 584 + p] = (short)f2bf(vsrc[d]);
  }

  int qbase = wid * 144;
  short8 qf[9];
  #pragma unroll
  for (int qt = 0; qt < 9; ++qt) {
    if (kg < 3) {
      const float* qs =
          base + (size_t)(qbase + qt * 16 + cl) * 288 + qoff + kg * 8;
      float4 a = *(const float4*)qs;
      float4 b = *(const float4*)(qs + 4);
      S8U t;
      t.u[0] = cvtpk(a.x * scale, a.y * scale);
      t.u[1] = cvtpk(a.z * scale, a.w * scale);
      t.u[2] = cvtpk(b.x * scale, b.y * scale);
      t.u[3] = cvtpk(b.z * scale, b.w * scale);
      qf[qt] = t.s;
    } else {
      qf[qt] = (short8){0, 0, 0, 0, 0, 0, 0, 0};
    }
  }
  __syncthreads();

  f32x4 acc[9][2];
  float m[9], l[9];
  #pragma unroll
  for (int qt = 0; qt < 9; ++qt) {
    acc[qt][0] = (f32x4){0.f, 0.f, 0.f, 0.f};
    acc[qt][1] = (f32x4){0.f, 0.f, 0.f, 0.f};
    m[qt] = -1e30f; l[qt] = 0.f;
  }
  short* pw = P_lds + wid * 5760;
  const f32x4 z4 = (f32x4){0.f, 0.f, 0.f, 0.f};

  for (int ch = 0; ch < 18; ++ch) {
    int key0 = ch * 32;
    short8 ka0 = *reinterpret_cast<const short8*>(
        &K_lds[(key0 + cl) * 40 + kg * 8]);
    short8 ka1 = *reinterpret_cast<const short8*>(
        &K_lds[(key0 + 16 + cl) * 40 + kg * 8]);
    #pragma unroll
    for (int qt = 0; qt < 9; ++qt) {
      f32x4 s0 = MFMA16(ka0, qf[qt], z4);
      f32x4 s1 = MFMA16(ka1, qf[qt], z4);
      float mx = fmaxf(fmaxf(fmaxf(s0[0], s0[1]), fmaxf(s0[2], s0[3])),
                       fmaxf(fmaxf(s1[0], s1[1]), fmaxf(s1[2], s1[3])));
      mx = fmaxf(mx, __shfl_xor(mx, 16));
      mx = fmaxf(mx, __shfl_xor(mx, 32));
      float mn = fmaxf(m[qt], mx);
      float corr = __expf(m[qt] - mn);
      float p0 = __expf(s0[0] - mn), p1 = __expf(s0[1] - mn);
      float p2 = __expf(s0[2] - mn), p3 = __expf(s0[3] - mn);
      float p4 = __expf(s1[0] - mn), p5 = __expf(s1[1] - mn);
      float p6 = __expf(s1[2] - mn), p7 = __expf(s1[3] - mn);
      float sum = ((p0 + p1) + (p2 + p3)) + ((p4 + p5) + (p6 + p7));
      sum += __shfl_xor(sum, 16);
      sum += __shfl_xor(sum, 32);
      l[qt] = l[qt] * corr + sum;
      m[qt] = mn;
      float c0 = __shfl(corr, kg * 4 + 0);
      float c1 = __shfl(corr, kg * 4 + 1);
      float c2 = __shfl(corr, kg * 4 + 2);
      float c3 = __shfl(corr, kg * 4 + 3);
      acc[qt][0][0] *= c0; acc[qt][0][1] *= c1;
      acc[qt][0][2] *= c2; acc[qt][0][3] *= c3;
      acc[qt][1][0] *= c0; acc[qt][1][1] *= c1;
      acc[qt][1][2] *= c2; acc[qt][1][3] *= c3;
      uint2v w0 = {cvtpk(p0, p1), cvtpk(p2, p3)};
      uint2v w1 = {cvtpk(p4, p5), cvtpk(p6, p7)};
      short* prow = pw + (qt * 16 + cl) * 40;
      *reinterpret_cast<uint2v*>(&prow[4 * kg]) = w0;
      *reinterpret_cast<uint2v*>(&prow[16 + 4 * kg]) = w1;
    }
    short8 vb0 = *reinterpret_cast<const short8*>(
        &VT_lds[cl * 584 + key0 + kg * 8]);
    short8 vb1 = (cl < 8) ? *reinterpret_cast<const short8*>(
                                &VT_lds[(16 + cl) * 584 + key0 + kg * 8])
                          : (short8){0, 0, 0, 0, 0, 0, 0, 0};
    #pragma unroll
    for (int qt = 0; qt < 9; ++qt) {
      short8 pa = *reinterpret_cast<const short8*>(
          &pw[(qt * 16 + cl) * 40 + kg * 8]);
      acc[qt][0] = MFMA16(pa, vb0, acc[qt][0]);
      acc[qt][1] = MFMA16(pa, vb1, acc[qt][1]);
    }
  }

  #pragma unroll
  for (int qt = 0; qt < 9; ++qt) {
    float li0 = 1.f / __shfl(l[qt], kg * 4 + 0);
    float li1 = 1.f / __shfl(l[qt], kg * 4 + 1);
    float li2 = 1.f / __shfl(l[qt], kg * 4 + 2);
    float li3 = 1.f / __shfl(l[qt], kg * 4 + 3);
    #pragma unroll
    for (int dt = 0; dt < 2; ++dt) {
      int d = dt * 16 + cl;
      if (dt == 1 && cl >= 8) continue;
      size_t ob = ((size_t)n * HWP + qbase + qt * 16 + kg * 4) * CC
                  + head * HDIM + d;
      o[ob] = acc[qt][dt][0] * li0;
      o[ob + CC] = acc[qt][dt][1] * li1;
      o[ob + 2 * CC] = acc[qt][dt][2] * li2;
      o[ob + 3 * CC] = acc[qt][dt][3] * li3;
    }
  }
}

// ---------------- proj + residual (MFMA) ----------------
__global__ __launch_bounds__(256) void k_proj(const float* __restrict__ o,
    const float* __restrict__ Wp, const float* __restrict__ bp,
    const float* __restrict__ x, float* __restrict__ y) {
  int id = blockIdx.x;
  int n = id & 63, pt = id >> 6;
  int p0 = pt * 96;
  __shared__ __align__(16) short XT[96 * 104];
  int tid = threadIdx.x, lane = tid & 63, wid = tid >> 6;
  int wr = wid >> 1, wcn = wid & 1;
  int cl = lane & 15, kg = lane >> 4;
  #pragma unroll
  for (int w = 0; w < 9; ++w) {
    int lin = tid + 256 * w;
    int p = lin / 24, cg = lin % 24;
    float4 v = *reinterpret_cast<const float4*>(
        &o[((size_t)n * HWP + p0 + p) * CC + cg * 4]);
    uint2v u = {cvtpk(v.x, v.y), cvtpk(v.z, v.w)};
    *reinterpret_cast<uint2v*>(&XT[p * 104 + cg * 4]) = u;
  }
  __syncthreads();

  f32x4 acc[3][3];
  #pragma unroll
  for (int mt = 0; mt < 3; ++mt)
    #pragma unroll
    for (int nt = 0; nt < 3; ++nt) acc[mt][nt] = (f32x4){0.f, 0.f, 0.f, 0.f};

  #pragma unroll
  for (int kc = 0; kc < 3; ++kc) {
    short8 af[3];
    #pragma unroll
    for (int mt = 0; mt < 3; ++mt) {
      int row = wr * 48 + mt * 16 + cl;
      af[mt] = *reinterpret_cast<const short8*>(
          &XT[row * 104 + kc * 32 + kg * 8]);
    }
    #pragma unroll
    for (int nt = 0; nt < 3; ++nt) {
      int j = wcn * 48 + nt * 16 + cl;
      const float* wp = Wp + (size_t)(kc * 32 + kg * 8) * 96 + j;
      S8U b;
      b.u[0] = cvtpk(wp[0], wp[96]);
      b.u[1] = cvtpk(wp[192], wp[288]);
      b.u[2] = cvtpk(wp[384], wp[480]);
      b.u[3] = cvtpk(wp[576], wp[672]);
      #pragma unroll
      for (int mt = 0; mt < 3; ++mt)
        acc[mt][nt] = MFMA16(af[mt], b.s, acc[mt][nt]);
    }
  }

  #pragma unroll
  for (int nt = 0; nt < 3; ++nt) {
    int j = wcn * 48 + nt * 16 + cl;
    float bias = bp[j];
    #pragma unroll
    for (int mt = 0; mt < 3; ++mt) {
      int pr = p0 + wr * 48 + mt * 16 + kg * 4;
      size_t yi = ((size_t)n * CC + j) * HWP + pr;
      float4 xv = *reinterpret_cast<const float4*>(&x[yi]);
      float4 o4 = {xv.x + acc[mt][nt][0] + bias, xv.y + acc[mt][nt][1] + bias,
                   xv.z + acc[mt][nt][2] + bias, xv.w + acc[mt][nt][3] + bias};
      *reinterpret_cast<float4*>(&y[yi]) = o4;
    }
  }
}

// ======================= MFMA convs (round-17, best) =======================
// 3-phase staging of 64 channels each: XT[170][68] shorts = 23.1 KB.

__global__ __launch_bounds__(256) void k_conv_zr(const float* __restrict__ y,
    const float* __restrict__ hidden, const int* __restrict__ keys,
    const short* __restrict__ wt, const float* __restrict__ bb,
    float* __restrict__ z, float* __restrict__ rh) {
  int id = blockIdx.x;
  int n = id & 63, b = id >> 6;
  int bp = b % 6, bo = b / 6;
  int key = keys[n];
  int ocb = bo * 96;
  __shared__ __align__(16) short XT[170 * 68];
  int tid = threadIdx.x;
  int lane = tid & 63, wid = tid >> 6;
  int wr = wid >> 1, wc = wid & 1;
  int col = lane & 15, kg = lane >> 4;
  int icp = tid >> 4, psub = tid & 15;
  int pg0 = (3 * bp - 1) * 32;
  unsigned int* XTu = reinterpret_cast<unsigned int*>(XT);

  for (int i = tid; i < 5780; i += 256) XTu[i] = 0;

  f32x4 acc[3][3];
  #pragma unroll
  for (int m = 0; m < 3; ++m)
    #pragma unroll
    for (int nt = 0; nt < 3; ++nt) acc[m][nt] = (f32x4){0.f, 0.f, 0.f, 0.f};
  int rowm[3], pxm[3];
  #pragma unroll
  for (int m = 0; m < 3; ++m) {
    int pl = wr * 48 + m * 16 + col;
    rowm[m] = pl >> 5;
    pxm[m] = pl & 31;
  }
  int wl = (ocb + wc * 48 + col) * 192 + kg * 8;
  const float* hsrc = hidden + (size_t)key * HIDC * HWP;
  __syncthreads();

  #pragma unroll
  for (int ph = 0; ph < 3; ++ph) {
    #pragma unroll
    for (int c = 0; c < 2; ++c) {
      int gc = ph * 64 + c * 32;
      const float* s0 = (gc < 96)
          ? y + ((size_t)n * CC + gc + 2 * icp) * HWP
          : hsrc + (size_t)(gc - 96 + 2 * icp) * HWP;
      const float* s1 = s0 + HWP;
      #pragma unroll
      for (int j = 0; j < 5; ++j) {
        int pos = 32 * j + 2 * psub;
        int pg = pg0 + pos;
        bool ok = (pg >= 0 && pg < HWP);
        float2 a = ok ? *reinterpret_cast<const float2*>(s0 + pg)
                      : float2{0.f, 0.f};
        float2 bv = ok ? *reinterpret_cast<const float2*>(s1 + pg)
                       : float2{0.f, 0.f};
        int pidx0 = j * 34 + 1 + 2 * psub;
        XTu[pidx0 * 34 + c * 16 + icp] = cvtpk(a.x, bv.x);
        XTu[(pidx0 + 1) * 34 + c * 16 + icp] = cvtpk(a.y, bv.y);
      }
    }
    __syncthreads();
    #pragma unroll 3
    for (int t = 0; t < 9; ++t) {
      int dyp = t / 3, dxp = t % 3;
      const short* wci = wt + wl + t * 36864 + ph * 64;
      #pragma unroll
      for (int qc = 0; qc < 2; ++qc) {
        short8 b0 = *reinterpret_cast<const short8*>(wci + qc * 32);
        short8 b1 = *reinterpret_cast<const short8*>(wci + qc * 32 + 3072);
        short8 b2 = *reinterpret_cast<const short8*>(wci + qc * 32 + 6144);
        #pragma unroll
        for (int m = 0; m < 3; ++m) {
          int pidx = (rowm[m] + dyp) * 34 + pxm[m] + dxp;
          short8 a = *reinterpret_cast<const short8*>(
              XT + pidx * 68 + qc * 32 + kg * 8);
          acc[m][0] = MFMA16(a, b0, acc[m][0]);
          acc[m][1] = MFMA16(a, b1, acc[m][1]);
          acc[m][2] = MFMA16(a, b2, acc[m][2]);
        }
      }
    }
    __syncthreads();
  }

  #pragma unroll
  for (int nt = 0; nt < 3; ++nt) {
    int oc = ocb + wc * 48 + nt * 16 + col;
    float bias = bb[oc];
    #pragma unroll
    for (int m = 0; m < 3; ++m) {
      int p0 = bp * 96 + wr * 48 + m * 16 + kg * 4;
      f32x4 v = acc[m][nt];
      float e0 = 1.f / (1.f + __expf(-(v[0] + bias)));
      float e1 = 1.f / (1.f + __expf(-(v[1] + bias)));
      float e2 = 1.f / (1.f + __expf(-(v[2] + bias)));
      float e3 = 1.f / (1.f + __expf(-(v[3] + bias)));
      if (oc < CC) {
        float4 o4 = {e0, e1, e2, e3};
        *reinterpret_cast<float4*>(&z[((size_t)n * CC + oc) * HWP + p0]) = o4;
      } else {
        int c2 = oc - CC;
        float4 h4 = *reinterpret_cast<const float4*>(
            &hidden[((size_t)key * HIDC + c2) * HWP + p0]);
        float4 o4 = {e0 * h4.x, e1 * h4.y, e2 * h4.z, e3 * h4.w};
        *reinterpret_cast<float4*>(&rh[((size_t)n * CC + c2) * HWP + p0]) = o4;
      }
    }
  }
}

__global__ __launch_bounds__(256) void k_conv_c(const float* __restrict__ y,
    const float* __restrict__ rh, const int* __restrict__ keys,
    const float* __restrict__ z, const float* __restrict__ hidden,
    const short* __restrict__ wt, const float* __restrict__ bb,
    float* __restrict__ hn) {
  int id = blockIdx.x;
  int n = id & 63, bp = id >> 6;
  int key = keys[n];
  __shared__ __align__(16) short XT[170 * 68];
  int tid = threadIdx.x;
  int lane = tid & 63, wid = tid >> 6;
  int wr = wid >> 1, wc = wid & 1;
  int col = lane & 15, kg = lane >> 4;
  int icp = tid >> 4, psub = tid & 15;
  int pg0 = (3 * bp - 1) * 32;
  unsigned int* XTu = reinterpret_cast<unsigned int*>(XT);

  for (int i = tid; i < 5780; i += 256) XTu[i] = 0;

  f32x4 acc[3][3];
  #pragma unroll
  for (int m = 0; m < 3; ++m)
    #pragma unroll
    for (int nt = 0; nt < 3; ++nt) acc[m][nt] = (f32x4){0.f, 0.f, 0.f, 0.f};
  int rowm[3], pxm[3];
  #pragma unroll
  for (int m = 0; m < 3; ++m) {
    int pl = wr * 48 + m * 16 + col;
    rowm[m] = pl >> 5;
    pxm[m] = pl & 31;
  }
  int wl = (wc * 48 + col) * 192 + kg * 8;
  const float* rsrc = rh + (size_t)n * CC * HWP;
  __syncthreads();

  #pragma unroll
  for (int ph = 0; ph < 3; ++ph) {
    #pragma unroll
    for (int c = 0; c < 2; ++c) {
      int gc = ph * 64 + c * 32;
      const float* s0 = (gc < 96)
          ? y + ((size_t)n * CC + gc + 2 * icp) * HWP
          : rsrc + (size_t)(gc - 96 + 2 * icp) * HWP;
      const float* s1 = s0 + HWP;
      #pragma unroll
      for (int j = 0; j < 5; ++j) {
        int pos = 32 * j + 2 * psub;
        int pg = pg0 + pos;
        bool ok = (pg >= 0 && pg < HWP);
        float2 a = ok ? *reinterpret_cast<const float2*>(s0 + pg)
                      : float2{0.f, 0.f};
        float2 bv = ok ? *reinterpret_cast<const float2*>(s1 + pg)
                       : float2{0.f, 0.f};
        int pidx0 = j * 34 + 1 + 2 * psub;
        XTu[pidx0 * 34 + c * 16 + icp] = cvtpk(a.x, bv.x);
        XTu[(pidx0 + 1) * 34 + c * 16 + icp] = cvtpk(a.y, bv.y);
      }
    }
    __syncthreads();
    #pragma unroll 3
    for (int t = 0; t < 9; ++t) {
      int dyp = t / 3, dxp = t % 3;
      const short* wci = wt + wl + t * 18432 + ph * 64;
      #pragma unroll
      for (int qc = 0; qc < 2; ++qc) {
        short8 b0 = *reinterpret_cast<const short8*>(wci + qc * 32);
        short8 b1 = *reinterpret_cast<const short8*>(wci + qc * 32 + 3072);
        short8 b2 = *reinterpret_cast<const short8*>(wci + qc * 32 + 6144);
        #pragma unroll
        for (int m = 0; m < 3; ++m) {
          int pidx = (rowm[m] + dyp) * 34 + pxm[m] + dxp;
          short8 a = *reinterpret_cast<const short8*>(
              XT + pidx * 68 + qc * 32 + kg * 8);
          acc[m][0] = MFMA16(a, b0, acc[m][0]);
          acc[m][1] = MFMA16(a, b1, acc[m][1]);
          acc[m][2] = MFMA16(a, b2, acc[m][2]);
        }
      }
    }
    __syncthreads();
  }

  #pragma unroll
  for (int nt = 0; nt < 3; ++nt) {
    int oc = wc * 48 + nt * 16 + col;
    float bias = bb[oc];
    #pragma unroll
    for (int m = 0; m < 3; ++m) {
      int p0 = bp * 96 + wr * 48 + m * 16 + kg * 4;
      f32x4 v = acc[m][nt];
      float c0 = tanhf(v[0] + bias);
      float c1 = tanhf(v[1] + bias);
      float c2v = tanhf(v[2] + bias);
      float c3 = tanhf(v[3] + bias);
      float4 z4 = *reinterpret_cast<const float4*>(
          &z[((size_t)n * CC + oc) * HWP + p0]);
      float4 h4 = *reinterpret_cast<const float4*>(
          &hidden[((size_t)key * HIDC + oc) * HWP + p0]);
      float4 o4 = {(1.f - z4.x) * h4.x + z4.x * c0,
                   (1.f - z4.y) * h4.y + z4.y * c1,
                   (1.f - z4.z) * h4.z + z4.z * c2v,
                   (1.f - z4.w) * h4.w + z4.w * c3};
      *reinterpret_cast<float4*>(&hn[((size_t)n * CC + oc) * HWP + p0]) = o4;
    }
  }
}

// ---------------- PosConv (MFMA) + fused 2x2 mean pool ----------------
__global__ __launch_bounds__(256) void k_enc(const float* __restrict__ hn,
    const float* __restrict__ pos, const float* __restrict__ Wp,
    float* __restrict__ part, float* __restrict__ out) {
  int id = blockIdx.x;
  int n = id & 63, pt = id >> 6;
  int p0 = pt * 96;
  __shared__ __align__(16) short XT[96 * 104];
  int tid = threadIdx.x, lane = tid & 63, wid = tid >> 6;
  int wr = wid >> 1, wcn = wid & 1;
  int cl = lane & 15, kg = lane >> 4;

  #pragma unroll
  for (int r = 0; r < 9; ++r) {
    int idx = id * 2304 + r * 256 + tid;
    int jj = idx & 15, ii = (idx >> 4) % 9, nc = idx / 144;
    const float* bsrc = hn + (size_t)nc * HWP + (2 * ii) * WW + 2 * jj;
    out[idx] = 0.25f * (bsrc[0] + bsrc[1] + bsrc[WW] + bsrc[WW + 1]);
  }

  #pragma unroll
  for (int w = 0; w < 9; ++w) {
    int lin = tid + 256 * w;
    int cp = lin / 48, pp = (lin % 48) * 2;
    float2 ha = *reinterpret_cast<const float2*>(
        &hn[((size_t)n * CC + 2 * cp) * HWP + p0 + pp]);
    float2 hb = *reinterpret_cast<const float2*>(
        &hn[((size_t)n * CC + 2 * cp + 1) * HWP + p0 + pp]);
    float2 pa = *reinterpret_cast<const float2*>(&pos[(2 * cp) * HWP + p0 + pp]);
    float2 pc = *reinterpret_cast<const float2*>(
        &pos[(2 * cp + 1) * HWP + p0 + pp]);
    *reinterpret_cast<unsigned int*>(&XT[pp * 104 + 2 * cp]) =
        cvtpk(ha.x + pa.x, hb.x + pc.x);
    *reinterpret_cast<unsigned int*>(&XT[(pp + 1) * 104 + 2 * cp]) =
        cvtpk(ha.y + pa.y, hb.y + pc.y);
  }
  __syncthreads();

  f32x4 acc[3][10];
  #pragma unroll
  for (int mt = 0; mt < 3; ++mt)
    #pragma unroll
    for (int nt = 0; nt < 10; ++nt) acc[mt][nt] = (f32x4){0.f, 0.f, 0.f, 0.f};

  #pragma unroll
  for (int kc = 0; kc < 3; ++kc) {
    short8 af[3];
    #pragma unroll
    for (int mt = 0; mt < 3; ++mt) {
      int row = wr * 48 + mt * 16 + cl;
      af[mt] = *reinterpret_cast<const short8*>(
          &XT[row * 104 + kc * 32 + kg * 8]);
    }
    #pragma unroll
    for (int nt = 0; nt < 10; ++nt) {
      int oc = wcn * 160 + nt * 16 + cl;
      const float* wp = Wp + (size_t)oc * CC + kc * 32 + kg * 8;
      float4 w0 = *reinterpret_cast<const float4*>(wp);
      float4 w1 = *reinterpret_cast<const float4*>(wp + 4);
      S8U b;
      b.u[0] = cvtpk(w0.x, w0.y); b.u[1] = cvtpk(w0.z, w0.w);
      b.u[2] = cvtpk(w1.x, w1.y); b.u[3] = cvtpk(w1.z, w1.w);
      #pragma unroll
      for (int mt = 0; mt < 3; ++mt)
        acc[mt][nt] = MFMA16(af[mt], b.s, acc[mt][nt]);
    }
  }

  #pragma unroll
  for (int nt = 0; nt < 10; ++nt) {
    float mx = -1e30f;
    #pragma unroll
    for (int mt = 0; mt < 3; ++mt) {
      mx = fmaxf(mx, fmaxf(fmaxf(acc[mt][nt][0], acc[mt][nt][1]),
                           fmaxf(acc[mt][nt][2], acc[mt][nt][3])));
    }
    mx = fmaxf(mx, __shfl_xor(mx, 16));
    mx = fmaxf(mx, __shfl_xor(mx, 32));
    if (kg == 0) {
      int oc = wcn * 160 + nt * 16 + cl;
      part[(((size_t)n * 6 + pt) * 2 + wr) * ENCC + oc] = mx;
    }
  }
}

__global__ __launch_bounds__(320) void k_reduce(const float* __restrict__ part,
    const float* __restrict__ bpos, float* __restrict__ out) {
  int n = blockIdx.x, o = threadIdx.x;
  float mx = -1e30f;
  #pragma unroll
  for (int t = 0; t < 12; ++t)
    mx = fmaxf(mx, part[((size_t)n * 12 + t) * ENCC + o]);
  out[NN * CC * 144 + n * ENCC + o] = mx + bpos[o];
}

extern "C" void kernel_launch(void* const* d_in, const int* in_sizes, int n_in,
                              void* d_out, int out_size, void* d_ws, size_t ws_size,
                              hipStream_t stream) {
  const float* x       = (const float*)d_in[0];
  const float* x_state = (const float*)d_in[1];
  const int*   keys    = (const int*)d_in[2];
  const float* hidden  = (const float*)d_in[3];
  const float* W_mod   = (const float*)d_in[4];
  const float* b_mod   = (const float*)d_in[5];
  const float* W_qkv   = (const float*)d_in[6];
  const float* b_qkv   = (const float*)d_in[7];
  const float* W_proj  = (const float*)d_in[8];
  const float* b_proj  = (const float*)d_in[9];
  const float* K_zr    = (const float*)d_in[10];
  const float* b_zr    = (const float*)d_in[11];
  const float* K_c     = (const float*)d_in[12];
  const float* b_c     = (const float*)d_in[13];
  const float* pos_emb = (const float*)d_in[14];
  const float* W_pos   = (const float*)d_in[15];
  const float* b_pos   = (const float*)d_in[16];
  float* out = (float*)d_out;
  float* ws  = (float*)d_ws;
  short* wtzr = (short*)(ws + WTZR_OFF);
  short* wtc  = (short*)(ws + WTC_OFF);

  k_modwt<<<280, 256, 0, stream>>>(x_state, W_mod, b_mod, ws + MOD_OFF,
                                   K_zr, K_c, wtzr, wtc);
  k_qkv<<<384, 256, 0, stream>>>(x, ws + MOD_OFF, W_qkv, b_qkv, ws + A_OFF);
  k_attn<<<256, 256, 0, stream>>>(ws + A_OFF, ws + O_OFF);
  k_proj<<<384, 256, 0, stream>>>(ws + O_OFF, W_proj, b_proj, x, ws + Y_OFF);
  k_conv_zr<<<768, 256, 0, stream>>>(ws + Y_OFF, hidden, keys, wtzr, b_zr,
                                     ws + Z_OFF, ws + RH_OFF);
  k_conv_c<<<384, 256, 0, stream>>>(ws + Y_OFF, ws + RH_OFF, keys, ws + Z_OFF,
                                    hidden, wtc, b_c, ws + HN_OFF);
  k_enc<<<384, 256, 0, stream>>>(ws + HN_OFF, pos_emb, W_pos, ws + PART_OFF,
                                 out);
  k_reduce<<<NN, 320, 0, stream>>>(ws + PART_OFF, b_pos, out);
}